// Round 7
// baseline (103.728 us; speedup 1.0000x reference)
//
#include <hip/hip_runtime.h>

// CLUB loss, algebraically collapsed (O(N*d), x read once):
//   out = -0.5/N * P + 0.5/N^2 * ( <Sx2,Sinv> - 2<Sx,Smuinv> + N*Smu2inv )
// Sinv[d]=sum_i e^{-lv}, Smuinv[d]=sum_i mu e^{-lv}, Sx[d]=sum_j x, Sx2[d]=sum_j x^2
// P = sum (x-mu)^2 e^{-lv},  Smu2inv = sum mu^2 e^{-lv}
//
// R7: barrier-free column-private accumulation. Thread owns ONE column d for
// 28 rows: mu/lv coalesced (lane-consecutive cols), x per-lane sequential
// (column-contiguous in x layout; float4 per 4 rows, line reuse from L1).
// No LDS transpose, no column reductions, no load mega-batches. 448 blocks,
// 6 scalar accumulators/thread, fire-and-forget atomics to 8 replicas,
// last-block-done finalize (device-scope counter, proven in R6).

#define Dd   512
#define HWs  784
#define Nn   6272
#define NBLK 448      // 8 b * 2 col-halves * 28 row-chunks (28 rows each)

// ws floats: Inv rep*512+c | Mu 4096+ | Sx 8192+ | Sx2 12288+  (rep<8)
// doubles @byte 65536: P[8], M2[8].  uint counter @byte 65664.

__global__ __launch_bounds__(256) void club_all(
    const float* __restrict__ x, const float* __restrict__ p_mu,
    const float* __restrict__ p_lv, float* __restrict__ ws,
    float* __restrict__ out)
{
    __shared__ float sbuf[16];
    __shared__ int lastFlag;
    __shared__ double redd[256];

    const int t     = threadIdx.x;
    const int blk   = blockIdx.x;
    const int b     = blk / 56;
    const int rem   = blk % 56;
    const int half  = rem & 1;
    const int chunk = rem >> 1;          // 0..27
    const int hw0   = chunk * 28;
    const int c     = 256 * half + t;    // this thread's column
    const int r0    = b * HWs + hw0;     // first flat row
    const int rep   = blk & 7;

    const float* xr = x + ((size_t)(b * Dd + c) * HWs + hw0);  // per-lane stream
    const float* mp = p_mu + (size_t)r0 * Dd + c;
    const float* lp = p_lv + (size_t)r0 * Dd + c;

    float sI = 0.f, sM = 0.f, sX = 0.f, sX2 = 0.f, aP = 0.f, aM2 = 0.f;

#pragma unroll
    for (int k = 0; k < 7; ++k) {
        const float4 xq = *(const float4*)(xr + 4 * k);
        const float xv0 = xq.x, xv1 = xq.y, xv2 = xq.z, xv3 = xq.w;
#define STEP(J, XV) do {                                               \
        const size_t ro = (size_t)(4 * k + (J)) * Dd;                  \
        const float mu = mp[ro];                                       \
        const float lv = lp[ro];                                       \
        const float iev = __expf(-lv);                                 \
        const float dd = (XV) - mu;                                    \
        aP += dd * dd * iev;                                           \
        sI += iev;                                                     \
        const float mi = mu * iev;                                     \
        sM += mi; aM2 += mu * mi;                                      \
        sX += (XV); sX2 += (XV) * (XV);                                \
    } while (0)
        STEP(0, xv0); STEP(1, xv1); STEP(2, xv2); STEP(3, xv3);
#undef STEP
    }

    // ---- scalar P/M2: wave shuffle -> LDS -> one double atomic each ----
#pragma unroll
    for (int off = 32; off > 0; off >>= 1) {
        aP  += __shfl_down(aP,  off);
        aM2 += __shfl_down(aM2, off);
    }
    if ((t & 63) == 0) { sbuf[t >> 6] = aP; sbuf[8 + (t >> 6)] = aM2; }
    __syncthreads();     // the ONLY barrier before the finalize

    // ---- fire-and-forget atomics: thread's own column, 8-way replicas ----
    atomicAdd(&ws[         rep * Dd + c], sI);
    atomicAdd(&ws[ 4096 + rep * Dd + c], sM);
    atomicAdd(&ws[ 8192 + rep * Dd + c], sX);
    atomicAdd(&ws[12288 + rep * Dd + c], sX2);
    if (t == 0) {
        double* wd = (double*)((char*)ws + 65536);
        atomicAdd(wd + rep,     (double)(sbuf[0] + sbuf[1] + sbuf[2] + sbuf[3]));
        atomicAdd(wd + 8 + rep, (double)(sbuf[8] + sbuf[9] + sbuf[10] + sbuf[11]));
    }

    // ---- last-block-done finalize (R6 machinery) ----
    if (t == 0) {
        __threadfence();
        unsigned* ctr = (unsigned*)((char*)ws + 65664);
        lastFlag = (atomicAdd(ctr, 1u) == NBLK - 1);
    }
    __syncthreads();
    if (!lastFlag) return;

    __threadfence();
    double dc = 0.0;
#pragma unroll
    for (int hh = 0; hh < 2; ++hh) {
        const int cc = t + 256 * hh;
        double vI = 0.0, vM = 0.0, vX = 0.0, v2 = 0.0;
#pragma unroll
        for (int r = 0; r < 8; ++r) {
            vI += (double)__hip_atomic_load(ws +         r * Dd + cc, __ATOMIC_RELAXED, __HIP_MEMORY_SCOPE_AGENT);
            vM += (double)__hip_atomic_load(ws +  4096 + r * Dd + cc, __ATOMIC_RELAXED, __HIP_MEMORY_SCOPE_AGENT);
            vX += (double)__hip_atomic_load(ws +  8192 + r * Dd + cc, __ATOMIC_RELAXED, __HIP_MEMORY_SCOPE_AGENT);
            v2 += (double)__hip_atomic_load(ws + 12288 + r * Dd + cc, __ATOMIC_RELAXED, __HIP_MEMORY_SCOPE_AGENT);
        }
        dc += v2 * vI - 2.0 * vX * vM;
    }
    redd[t] = dc; __syncthreads();
    for (int s = 128; s > 0; s >>= 1) {
        if (t < s) redd[t] += redd[t + s];
        __syncthreads();
    }
    if (t == 0) {
        double* wd = (double*)((char*)ws + 65536);
        double P = 0.0, M2 = 0.0;
#pragma unroll
        for (int r = 0; r < 8; ++r) {
            P  += __hip_atomic_load(wd + r,     __ATOMIC_RELAXED, __HIP_MEMORY_SCOPE_AGENT);
            M2 += __hip_atomic_load(wd + 8 + r, __ATOMIC_RELAXED, __HIP_MEMORY_SCOPE_AGENT);
        }
        const double sumD = redd[0] + (double)Nn * M2;
        out[0] = (float)((-0.5 / (double)Nn) * P
                       + (0.5 / ((double)Nn * (double)Nn)) * sumD);
    }
}

extern "C" void kernel_launch(void* const* d_in, const int* in_sizes, int n_in,
                              void* d_out, int out_size, void* d_ws, size_t ws_size,
                              hipStream_t stream) {
    const float* x    = (const float*)d_in[0];
    const float* p_mu = (const float*)d_in[1];
    const float* p_lv = (const float*)d_in[2];
    float* ws = (float*)d_ws;

    // zero: 64KB float accumulators + 16 doubles + counter
    hipMemsetAsync(d_ws, 0, 65668, stream);
    club_all<<<NBLK, 256, 0, stream>>>(x, p_mu, p_lv, ws, (float*)d_out);
}